// Round 4
// baseline (1589.694 us; speedup 1.0000x reference)
//
#include <hip/hip_runtime.h>
#include <hip/hip_bf16.h>
#include <math.h>

#define N_NODES 100000
#define N_EDGES 3200000
#define NODE_IN 118
#define DIM 32
#define EDF 53
#define NLAYER 4

typedef __attribute__((ext_vector_type(8))) short short8;
typedef __attribute__((ext_vector_type(4))) short short4v;
typedef __attribute__((ext_vector_type(4))) float f32x4;
typedef unsigned short u16;
typedef unsigned int u32;

static __device__ __forceinline__ float bfhi2f(u32 hi) {   // bf16 in high 16 bits
    union { u32 i; float f; } x; x.i = hi; return x.f;
}
static __device__ __forceinline__ u16 f2bf(float f) {
    union { float f; u32 i; } x; x.f = f;
    u32 i = x.i;
    return (u16)((i + 0x7FFFu + ((i >> 16) & 1u)) >> 16);
}

// ---------------- CSR build ----------------
__global__ __launch_bounds__(256) void k_count(const int* __restrict__ dst, int* __restrict__ cnt) {
    int e = blockIdx.x * 256 + threadIdx.x;
    atomicAdd(&cnt[dst[e]], 1);
}

__global__ __launch_bounds__(256) void k_scanA(const int* __restrict__ cnt, int* __restrict__ off,
                                               int* __restrict__ bsum) {
    __shared__ int s[256];
    int t = threadIdx.x; int i = blockIdx.x * 256 + t;
    int v = (i < N_NODES) ? cnt[i] : 0;
    s[t] = v; __syncthreads();
    for (int d = 1; d < 256; d <<= 1) {
        int x = (t >= d) ? s[t - d] : 0; __syncthreads();
        s[t] += x; __syncthreads();
    }
    if (i < N_NODES) off[i] = s[t] - v;
    if (t == 255) bsum[blockIdx.x] = s[t];
}

__global__ __launch_bounds__(512) void k_scanB(int* bsum, int nb) {
    __shared__ int s[512];
    int t = threadIdx.x;
    int v = (t < nb) ? bsum[t] : 0;
    s[t] = v; __syncthreads();
    for (int d = 1; d < 512; d <<= 1) {
        int x = (t >= d) ? s[t - d] : 0; __syncthreads();
        s[t] += x; __syncthreads();
    }
    if (t < nb) bsum[t] = s[t] - v;
}

__global__ __launch_bounds__(256) void k_scanC(int* off, const int* __restrict__ bsum) {
    int i = blockIdx.x * 256 + threadIdx.x;
    if (i < N_NODES) off[i] += bsum[blockIdx.x];
    if (i == 0) off[N_NODES] = N_EDGES;
}

__global__ __launch_bounds__(256) void k_fill(const int* __restrict__ src, const int* __restrict__ dst,
                                              const int* __restrict__ off, int* __restrict__ cur,
                                              int* __restrict__ rank, int* __restrict__ esrc) {
    int e = blockIdx.x * 256 + threadIdx.x;
    int d = dst[e];
    int p = off[d] + atomicAdd(&cur[d], 1);
    rank[e] = p;            // edge -> CSR position
    esrc[p] = src[e];       // CSR-ordered source node
}

// ---------------- node input projection: h = x @ W + b ----------------
__global__ __launch_bounds__(256) void k_init(const float* __restrict__ x, const float* __restrict__ W,
                                              const float* __restrict__ b, float* __restrict__ h) {
    __shared__ float Ws[NODE_IN * DIM];
    __shared__ float xs[8][NODE_IN];
    int t = threadIdx.x;
    for (int i = t; i < NODE_IN * DIM; i += 256) Ws[i] = W[i];
    int nb = blockIdx.x * 8;
    for (int i = t; i < 8 * NODE_IN; i += 256) {
        int n = i / NODE_IN, j = i % NODE_IN;
        xs[n][j] = x[(size_t)(nb + n) * NODE_IN + j];
    }
    __syncthreads();
    int n = t >> 5, c = t & 31;
    float acc = b[c];
    #pragma unroll 2
    for (int j = 0; j < NODE_IN; j++) acc += xs[n][j] * Ws[j * DIM + c];
    h[(size_t)(nb + n) * DIM + c] = acc;
}

// ---------------- edge-feature GEMM: SEQUENTIAL reads, CSR scatter-store ----------------
// Reads ef rows in natural edge order (fully coalesced, no dependent loads);
// swapped-operand MFMA -> lane holds 4 consecutive channels of one edge; stores the
// 64B output row at its CSR rank (fire-and-forget scatter, never stalls the pipe).
template <int NL>
__global__ __launch_bounds__(256) void k_egemm(const float* __restrict__ elen, const float* __restrict__ evec,
                                               const int* __restrict__ rank, const float* __restrict__ We,
                                               u16* __restrict__ eout) {
    int tid = threadIdx.x;
    int lane = tid & 63;
    int wv = (blockIdx.x * 256 + tid) >> 6;
    int nw = (gridDim.x * 256) >> 6;
    int n15 = lane & 15, kb = lane >> 4;

    // We fragments (K padded to 64), VGPR-resident.
    short8 bf[2][2 * NL];
    for (int s = 0; s < 2; s++) {
        for (int t = 0; t < 2 * NL; t++) {
            int n = t * 16 + n15;
            int lay = n >> 5, c = n & 31;
            short8 tmp;
            #pragma unroll
            for (int j = 0; j < 8; j++) {
                int kk = s * 32 + kb * 8 + j;
                float w = (kk < EDF) ? We[(size_t)lay * EDF * DIM + (size_t)kk * DIM + c] : 0.f;
                ((u16*)&tmp)[j] = f2bf(w);
            }
            bf[s][t] = tmp;
        }
    }

    const int NT = N_EDGES / 16;

    auto LOADA = [&](int tile, float* fv, int& rk) {
        int pos = tile * 16 + n15;
        rk = rank[pos];
        const float* lp = elen + (size_t)pos * 50;
        {
            const float2* p2 = (const float2*)(lp + kb * 8);
            #pragma unroll
            for (int j = 0; j < 4; j++) { float2 t2 = p2[j]; fv[2 * j] = t2.x; fv[2 * j + 1] = t2.y; }
        }
        if (kb < 2) {
            const float2* p2 = (const float2*)(lp + 32 + kb * 8);
            #pragma unroll
            for (int j = 0; j < 4; j++) { float2 t2 = p2[j]; fv[8 + 2 * j] = t2.x; fv[8 + 2 * j + 1] = t2.y; }
        } else if (kb == 2) {
            float2 t2 = *(const float2*)(lp + 48);
            const float* vp = evec + (size_t)pos * 3;
            fv[8] = t2.x; fv[9] = t2.y; fv[10] = vp[0]; fv[11] = vp[1]; fv[12] = vp[2];
            fv[13] = 0.f; fv[14] = 0.f; fv[15] = 0.f;
        } else {
            #pragma unroll
            for (int j = 8; j < 16; j++) fv[j] = 0.f;
        }
    };

    float cur[16]; int rkc = 0;
    if (wv < NT) LOADA(wv, cur, rkc);

    for (int tile = wv; tile < NT; tile += nw) {
        int nxt = tile + nw;
        float nx[16]; int rkn = rkc;
        if (nxt < NT) LOADA(nxt, nx, rkn);   // next-tile loads in flight during this tile's work

        short8 af[2];
        #pragma unroll
        for (int s = 0; s < 2; s++) {
            short8 tmp;
            #pragma unroll
            for (int j = 0; j < 8; j++) ((u16*)&tmp)[j] = f2bf(cur[s * 8 + j]);
            af[s] = tmp;
        }

        size_t rowbase = (size_t)rkc * DIM;
        #pragma unroll
        for (int t = 0; t < 2 * NL; t++) {
            f32x4 z = {0.f, 0.f, 0.f, 0.f};
            // swapped operands: C col = lane&15 = edge, C row = kb*4 + r = channel
            z = __builtin_amdgcn_mfma_f32_16x16x32_bf16(bf[0][t], af[0], z, 0, 0, 0);
            z = __builtin_amdgcn_mfma_f32_16x16x32_bf16(bf[1][t], af[1], z, 0, 0, 0);
            int lay = t >> 1;
            int ch = (t & 1) * 16 + kb * 4;
            short4v sv;
            #pragma unroll
            for (int r = 0; r < 4; r++) ((u16*)&sv)[r] = f2bf(z[r]);
            *(short4v*)&eout[(size_t)lay * N_EDGES * DIM + rowbase + ch] = sv;
        }

        #pragma unroll
        for (int j = 0; j < 16; j++) cur[j] = nx[j];
        rkc = rkn;
    }
}

// ---------------- per-layer node transform: LN + q,k,v,skip ----------------
__global__ __launch_bounds__(256) void k_node(const float* __restrict__ h,
        const float* __restrict__ g, const float* __restrict__ bta,
        const float* __restrict__ Wq, const float* __restrict__ bq,
        const float* __restrict__ Wk, const float* __restrict__ bk,
        const float* __restrict__ Wv, const float* __restrict__ bv,
        const float* __restrict__ Ws, const float* __restrict__ bs,
        float* __restrict__ qo, float* __restrict__ ko, float* __restrict__ vo, float* __restrict__ so) {
    __shared__ float WQ[DIM * DIM], WK[DIM * DIM], WV[DIM * DIM], WS[DIM * DIM];
    __shared__ float xn[8][DIM];
    int t = threadIdx.x;
    for (int i = t; i < DIM * DIM; i += 256) { WQ[i] = Wq[i]; WK[i] = Wk[i]; WV[i] = Wv[i]; WS[i] = Ws[i]; }
    int n = t >> 5, c = t & 31;
    size_t node = (size_t)blockIdx.x * 8 + n;
    float hv = h[node * DIM + c];
    float s1 = hv;
    for (int d = 1; d < 32; d <<= 1) s1 += __shfl_xor(s1, d, 64);
    float mu = s1 * (1.f / 32.f);
    float dv = hv - mu;
    float s2 = dv * dv;
    for (int d = 1; d < 32; d <<= 1) s2 += __shfl_xor(s2, d, 64);
    float inv = rsqrtf(s2 * (1.f / 32.f) + 1e-5f);
    float xv = dv * inv * g[c] + bta[c];
    xn[n][c] = xv;
    __syncthreads();
    float aq = bq[c], ak = bk[c], av = bv[c], as = bs[c];
    #pragma unroll 4
    for (int j = 0; j < DIM; j++) {
        float xj = xn[n][j];
        aq += xj * WQ[j * DIM + c];
        ak += xj * WK[j * DIM + c];
        av += xj * WV[j * DIM + c];
        as += xj * WS[j * DIM + c];
    }
    size_t o = node * DIM + c;
    qo[o] = aq; ko[o] = ak; vo[o] = av; so[o] = as;
}

// ---------------- per-layer edge aggregation: wave/node, 8 edges/iter, pipelined ----------------
// lane = (edge-group eg = lane>>3, channel quad cq = lane&7 -> channels cq*4..cq*4+3)
// depth-2 prefetch on esrc index, depth-1 on eb/k/v data: loads for iter i+1 issue
// before the compute of iter i, so the esrc->kv dependent chain is off the critical path.
__global__ __launch_bounds__(256) void k_aggr(const int* __restrict__ off, const int* __restrict__ esrc,
        const u16* __restrict__ eb,
        const float* __restrict__ qb, const float* __restrict__ kb, const float* __restrict__ vb,
        const float* __restrict__ h, const float* __restrict__ sk, float* __restrict__ out) {
    int tid = threadIdx.x;
    size_t node = (size_t)blockIdx.x * 4 + (tid >> 6);
    int lane = tid & 63;
    int eg = lane >> 3, cq = lane & 7, c0 = cq * 4;
    const float scale = 0.35355339059327373f;  // 1/sqrt(8)
    float4 qv = *(const float4*)&qb[node * DIM + c0];
    qv.x *= scale; qv.y *= scale; qv.z *= scale; qv.w *= scale;
    int o0 = off[node], o1 = off[node + 1];
    float4 nacc = {0.f, 0.f, 0.f, 0.f};
    float dacc = 0.f;

    // prefetch iter 0 data + iter 1 index
    int p1 = o0 + eg;
    bool a1 = p1 < o1; int pc1 = a1 ? p1 : o0;
    int sj1 = esrc[pc1];
    uint2 eb1 = *(const uint2*)&eb[(size_t)pc1 * DIM + c0];
    float4 kv1 = *(const float4*)&kb[(size_t)sj1 * DIM + c0];
    float4 vv1 = *(const float4*)&vb[(size_t)sj1 * DIM + c0];
    int p2 = p1 + 8;
    bool a2 = p2 < o1; int pc2 = a2 ? p2 : o0;
    int sj2 = esrc[pc2];

    for (int p0 = o0; p0 < o1; p0 += 8) {
        // issue next-iter data loads (independent of current compute)
        uint2 ebn = *(const uint2*)&eb[(size_t)pc2 * DIM + c0];
        float4 kvn = *(const float4*)&kb[(size_t)sj2 * DIM + c0];
        float4 vvn = *(const float4*)&vb[(size_t)sj2 * DIM + c0];
        // issue index load for iter+2
        int p3 = p2 + 8;
        bool a3 = p3 < o1; int pc3 = a3 ? p3 : o0;
        int sj3 = esrc[pc3];

        // compute current
        float e0 = bfhi2f(eb1.x << 16), e1 = bfhi2f(eb1.x & 0xFFFF0000u);
        float e2 = bfhi2f(eb1.y << 16), e3 = bfhi2f(eb1.y & 0xFFFF0000u);
        float a = qv.x * (kv1.x + e0);
        a = fmaf(qv.y, kv1.y + e1, a);
        a = fmaf(qv.z, kv1.z + e2, a);
        a = fmaf(qv.w, kv1.w + e3, a);
        a += __shfl_xor(a, 1);           // pair covers the head's 8 channels
        float ex = a1 ? __expf(a) : 0.f;
        nacc.x = fmaf(ex, vv1.x + e0, nacc.x);
        nacc.y = fmaf(ex, vv1.y + e1, nacc.y);
        nacc.z = fmaf(ex, vv1.z + e2, nacc.z);
        nacc.w = fmaf(ex, vv1.w + e3, nacc.w);
        dacc += ex;

        // rotate pipeline
        a1 = a2; eb1 = ebn; kv1 = kvn; vv1 = vvn;
        a2 = a3; pc2 = pc3; sj2 = sj3; p2 = p3;
    }
    // reduce across the 8 edge-groups (cq preserved)
    #pragma unroll
    for (int d = 8; d < 64; d <<= 1) {
        nacc.x += __shfl_xor(nacc.x, d);
        nacc.y += __shfl_xor(nacc.y, d);
        nacc.z += __shfl_xor(nacc.z, d);
        nacc.w += __shfl_xor(nacc.w, d);
        dacc   += __shfl_xor(dacc, d);
    }
    if (eg == 0) {
        float inv = 1.f / (dacc + 1e-16f);
        float4 hv = *(const float4*)&h[node * DIM + c0];
        float4 sv = *(const float4*)&sk[node * DIM + c0];
        float4 o;
        o.x = hv.x + nacc.x * inv + sv.x;
        o.y = hv.y + nacc.y * inv + sv.y;
        o.z = hv.z + nacc.z * inv + sv.z;
        o.w = hv.w + nacc.w * inv + sv.w;
        *(float4*)&out[node * DIM + c0] = o;
    }
}

extern "C" void kernel_launch(void* const* d_in, const int* in_sizes, int n_in,
                              void* d_out, int out_size, void* d_ws, size_t ws_size,
                              hipStream_t stream) {
    const float* x    = (const float*)d_in[0];
    const int*   ei   = (const int*)d_in[1];
    const int*   src  = ei;
    const int*   dst  = ei + N_EDGES;
    const float* elen = (const float*)d_in[2];
    const float* evec = (const float*)d_in[3];
    const float* niW  = (const float*)d_in[4];
    const float* nib  = (const float*)d_in[5];
    const float* lng  = (const float*)d_in[6];
    const float* lnb  = (const float*)d_in[7];
    const float* Wq   = (const float*)d_in[8];
    const float* bq   = (const float*)d_in[9];
    const float* Wk   = (const float*)d_in[10];
    const float* bk   = (const float*)d_in[11];
    const float* Wv   = (const float*)d_in[12];
    const float* bv   = (const float*)d_in[13];
    const float* We   = (const float*)d_in[14];
    const float* Wsk  = (const float*)d_in[15];
    const float* bsk  = (const float*)d_in[16];
    float* out = (float*)d_out;

    unsigned char* w = (unsigned char*)d_ws;
    auto alloc = [&](size_t bytes) -> void* {
        void* p = (void*)w; w += (bytes + 255) & ~(size_t)255; return p;
    };
    int*   off  = (int*)alloc((N_NODES + 1) * sizeof(int));
    int*   cnt  = (int*)alloc(N_NODES * sizeof(int));       // reused as cursor
    int*   bsum = (int*)alloc(512 * sizeof(int));
    int*   rank = (int*)alloc((size_t)N_EDGES * sizeof(int));
    int*   esrc = (int*)alloc((size_t)N_EDGES * sizeof(int));
    float* h    = (float*)alloc((size_t)N_NODES * DIM * sizeof(float));
    float* qb   = (float*)alloc((size_t)N_NODES * DIM * sizeof(float));
    float* kb   = (float*)alloc((size_t)N_NODES * DIM * sizeof(float));
    float* vb   = (float*)alloc((size_t)N_NODES * DIM * sizeof(float));
    float* skb  = (float*)alloc((size_t)N_NODES * DIM * sizeof(float));
    size_t used = (size_t)(w - (unsigned char*)d_ws);
    size_t e_full = (size_t)NLAYER * N_EDGES * DIM * sizeof(u16);
    size_t e_one  = (size_t)N_EDGES * DIM * sizeof(u16);
    bool full = (used + e_full) <= ws_size;
    u16* ebuf = (u16*)alloc(full ? e_full : e_one);

    const int EB = N_EDGES / 256;   // 12500
    const int NB = N_NODES / 8;     // 12500
    const int AB = N_NODES / 4;     // 25000
    const int nbScan = (N_NODES + 255) / 256;  // 391

    // CSR build
    hipMemsetAsync(cnt, 0, N_NODES * sizeof(int), stream);
    k_count<<<EB, 256, 0, stream>>>(dst, cnt);
    k_scanA<<<nbScan, 256, 0, stream>>>(cnt, off, bsum);
    k_scanB<<<1, 512, 0, stream>>>(bsum, nbScan);
    k_scanC<<<nbScan, 256, 0, stream>>>(off, bsum);
    hipMemsetAsync(cnt, 0, N_NODES * sizeof(int), stream);
    k_fill<<<EB, 256, 0, stream>>>(src, dst, off, cnt, rank, esrc);

    // input projection
    k_init<<<NB, 256, 0, stream>>>(x, niW, nib, h);

    // edge-feature GEMM: sequential reads, CSR scatter-store
    if (full) k_egemm<4><<<4096, 256, 0, stream>>>(elen, evec, rank, We, ebuf);

    for (int l = 0; l < NLAYER; l++) {
        if (!full) k_egemm<1><<<4096, 256, 0, stream>>>(elen, evec, rank, We + (size_t)l * EDF * DIM, ebuf);
        k_node<<<NB, 256, 0, stream>>>(h, lng + l * DIM, lnb + l * DIM,
                                       Wq + (size_t)l * DIM * DIM, bq + l * DIM,
                                       Wk + (size_t)l * DIM * DIM, bk + l * DIM,
                                       Wv + (size_t)l * DIM * DIM, bv + l * DIM,
                                       Wsk + (size_t)l * DIM * DIM, bsk + l * DIM,
                                       qb, kb, vb, skb);
        const u16* el = full ? (ebuf + (size_t)l * N_EDGES * DIM) : ebuf;
        k_aggr<<<AB, 256, 0, stream>>>(off, esrc, el, qb, kb, vb, h, skb,
                                       (l == NLAYER - 1) ? out : h);
    }
}

// Round 5
// 1574.374 us; speedup vs baseline: 1.0097x; 1.0097x over previous
//
#include <hip/hip_runtime.h>
#include <hip/hip_bf16.h>
#include <math.h>

#define N_NODES 100000
#define N_EDGES 3200000
#define NODE_IN 118
#define DIM 32
#define EDF 53
#define NLAYER 4

typedef __attribute__((ext_vector_type(8))) short short8;
typedef __attribute__((ext_vector_type(4))) short short4v;
typedef __attribute__((ext_vector_type(4))) float f32x4;
typedef unsigned short u16;
typedef unsigned int u32;

static __device__ __forceinline__ float bfhi2f(u32 hi) {   // bf16 bits (maybe in low16): pass pre-shifted
    union { u32 i; float f; } x; x.i = hi; return x.f;
}
static __device__ __forceinline__ u16 f2bf(float f) {
    union { float f; u32 i; } x; x.f = f;
    u32 i = x.i;
    return (u16)((i + 0x7FFFu + ((i >> 16) & 1u)) >> 16);
}

// ---------------- CSR build ----------------
__global__ __launch_bounds__(256) void k_count(const int* __restrict__ dst, int* __restrict__ cnt) {
    int e = blockIdx.x * 256 + threadIdx.x;
    atomicAdd(&cnt[dst[e]], 1);
}

__global__ __launch_bounds__(256) void k_scanA(const int* __restrict__ cnt, int* __restrict__ off,
                                               int* __restrict__ bsum) {
    __shared__ int s[256];
    int t = threadIdx.x; int i = blockIdx.x * 256 + t;
    int v = (i < N_NODES) ? cnt[i] : 0;
    s[t] = v; __syncthreads();
    for (int d = 1; d < 256; d <<= 1) {
        int x = (t >= d) ? s[t - d] : 0; __syncthreads();
        s[t] += x; __syncthreads();
    }
    if (i < N_NODES) off[i] = s[t] - v;
    if (t == 255) bsum[blockIdx.x] = s[t];
}

__global__ __launch_bounds__(512) void k_scanB(int* bsum, int nb) {
    __shared__ int s[512];
    int t = threadIdx.x;
    int v = (t < nb) ? bsum[t] : 0;
    s[t] = v; __syncthreads();
    for (int d = 1; d < 512; d <<= 1) {
        int x = (t >= d) ? s[t - d] : 0; __syncthreads();
        s[t] += x; __syncthreads();
    }
    if (t < nb) bsum[t] = s[t] - v;
}

__global__ __launch_bounds__(256) void k_scanC(int* off, const int* __restrict__ bsum) {
    int i = blockIdx.x * 256 + threadIdx.x;
    if (i < N_NODES) off[i] += bsum[blockIdx.x];
    if (i == 0) off[N_NODES] = N_EDGES;
}

__global__ __launch_bounds__(256) void k_fill(const int* __restrict__ src, const int* __restrict__ dst,
                                              const int* __restrict__ off, int* __restrict__ cur,
                                              int* __restrict__ eidx, int* __restrict__ esrc) {
    int e = blockIdx.x * 256 + threadIdx.x;
    int d = dst[e];
    int p = off[d] + atomicAdd(&cur[d], 1);
    eidx[p] = e;            // CSR position -> natural edge id
    esrc[p] = src[e];       // CSR-ordered source node
}

// ---------------- node input projection: h = x @ W + b ----------------
__global__ __launch_bounds__(256) void k_init(const float* __restrict__ x, const float* __restrict__ W,
                                              const float* __restrict__ b, float* __restrict__ h) {
    __shared__ float Ws[NODE_IN * DIM];
    __shared__ float xs[8][NODE_IN];
    int t = threadIdx.x;
    for (int i = t; i < NODE_IN * DIM; i += 256) Ws[i] = W[i];
    int nb = blockIdx.x * 8;
    for (int i = t; i < 8 * NODE_IN; i += 256) {
        int n = i / NODE_IN, j = i % NODE_IN;
        xs[n][j] = x[(size_t)(nb + n) * NODE_IN + j];
    }
    __syncthreads();
    int n = t >> 5, c = t & 31;
    float acc = b[c];
    #pragma unroll 2
    for (int j = 0; j < NODE_IN; j++) acc += xs[n][j] * Ws[j * DIM + c];
    h[(size_t)(nb + n) * DIM + c] = acc;
}

// ---------------- edge-feature GEMM: fully sequential in AND out ----------------
// Natural edge order on both sides: coalesced streaming reads of ef, coalesced
// streaming stores of e (bf16). No gathers, no scatters, no LDS.
template <int NL>
__global__ __launch_bounds__(256) void k_egemm(const float* __restrict__ elen, const float* __restrict__ evec,
                                               const float* __restrict__ We, u16* __restrict__ eout) {
    int tid = threadIdx.x;
    int lane = tid & 63;
    int wv = (blockIdx.x * 256 + tid) >> 6;
    int nw = (gridDim.x * 256) >> 6;
    int n15 = lane & 15, kb = lane >> 4;

    // We fragments (K padded to 64), VGPR-resident.
    short8 bf[2][2 * NL];
    for (int s = 0; s < 2; s++) {
        for (int t = 0; t < 2 * NL; t++) {
            int n = t * 16 + n15;
            int lay = n >> 5, c = n & 31;
            short8 tmp;
            #pragma unroll
            for (int j = 0; j < 8; j++) {
                int kk = s * 32 + kb * 8 + j;
                float w = (kk < EDF) ? We[(size_t)lay * EDF * DIM + (size_t)kk * DIM + c] : 0.f;
                ((u16*)&tmp)[j] = f2bf(w);
            }
            bf[s][t] = tmp;
        }
    }

    const int NT = N_EDGES / 16;

    auto LOADA = [&](int tile, float* fv) {
        int pos = tile * 16 + n15;
        const float* lp = elen + (size_t)pos * 50;
        {
            const float2* p2 = (const float2*)(lp + kb * 8);
            #pragma unroll
            for (int j = 0; j < 4; j++) { float2 t2 = p2[j]; fv[2 * j] = t2.x; fv[2 * j + 1] = t2.y; }
        }
        if (kb < 2) {
            const float2* p2 = (const float2*)(lp + 32 + kb * 8);
            #pragma unroll
            for (int j = 0; j < 4; j++) { float2 t2 = p2[j]; fv[8 + 2 * j] = t2.x; fv[8 + 2 * j + 1] = t2.y; }
        } else if (kb == 2) {
            float2 t2 = *(const float2*)(lp + 48);
            const float* vp = evec + (size_t)pos * 3;
            fv[8] = t2.x; fv[9] = t2.y; fv[10] = vp[0]; fv[11] = vp[1]; fv[12] = vp[2];
            fv[13] = 0.f; fv[14] = 0.f; fv[15] = 0.f;
        } else {
            #pragma unroll
            for (int j = 8; j < 16; j++) fv[j] = 0.f;
        }
    };

    float cur[16];
    if (wv < NT) LOADA(wv, cur);

    for (int tile = wv; tile < NT; tile += nw) {
        int nxt = tile + nw;
        float nx[16];
        if (nxt < NT) LOADA(nxt, nx);   // next-tile loads in flight during this tile's work

        short8 af[2];
        #pragma unroll
        for (int s = 0; s < 2; s++) {
            short8 tmp;
            #pragma unroll
            for (int j = 0; j < 8; j++) ((u16*)&tmp)[j] = f2bf(cur[s * 8 + j]);
            af[s] = tmp;
        }

        size_t rowbase = ((size_t)tile * 16 + n15) * DIM;
        #pragma unroll
        for (int t = 0; t < 2 * NL; t++) {
            f32x4 z = {0.f, 0.f, 0.f, 0.f};
            // swapped operands: C col = lane&15 = edge, C row = kb*4 + r = channel
            z = __builtin_amdgcn_mfma_f32_16x16x32_bf16(bf[0][t], af[0], z, 0, 0, 0);
            z = __builtin_amdgcn_mfma_f32_16x16x32_bf16(bf[1][t], af[1], z, 0, 0, 0);
            int lay = t >> 1;
            int ch = (t & 1) * 16 + kb * 4;
            short4v sv;
            #pragma unroll
            for (int r = 0; r < 4; r++) ((u16*)&sv)[r] = f2bf(z[r]);
            *(short4v*)&eout[(size_t)lay * N_EDGES * DIM + rowbase + ch] = sv;
        }

        #pragma unroll
        for (int j = 0; j < 16; j++) cur[j] = nx[j];
    }
}

// ---------------- per-layer node transform: LN + q,k,v,h+skip ----------------
// q pre-scaled by 1/sqrt(C); k,v in bf16 (halves aggr's gather bytes); hs = h + skip.
__global__ __launch_bounds__(256) void k_node(const float* __restrict__ h,
        const float* __restrict__ g, const float* __restrict__ bta,
        const float* __restrict__ Wq, const float* __restrict__ bq,
        const float* __restrict__ Wk, const float* __restrict__ bk,
        const float* __restrict__ Wv, const float* __restrict__ bv,
        const float* __restrict__ Ws, const float* __restrict__ bs,
        float* __restrict__ qo, u16* __restrict__ ko, u16* __restrict__ vo, float* __restrict__ hso) {
    __shared__ float WQ[DIM * DIM], WK[DIM * DIM], WV[DIM * DIM], WS[DIM * DIM];
    __shared__ float xn[8][DIM];
    int t = threadIdx.x;
    for (int i = t; i < DIM * DIM; i += 256) { WQ[i] = Wq[i]; WK[i] = Wk[i]; WV[i] = Wv[i]; WS[i] = Ws[i]; }
    int n = t >> 5, c = t & 31;
    size_t node = (size_t)blockIdx.x * 8 + n;
    float hv = h[node * DIM + c];
    float s1 = hv;
    for (int d = 1; d < 32; d <<= 1) s1 += __shfl_xor(s1, d, 64);
    float mu = s1 * (1.f / 32.f);
    float dv = hv - mu;
    float s2 = dv * dv;
    for (int d = 1; d < 32; d <<= 1) s2 += __shfl_xor(s2, d, 64);
    float inv = rsqrtf(s2 * (1.f / 32.f) + 1e-5f);
    float xv = dv * inv * g[c] + bta[c];
    xn[n][c] = xv;
    __syncthreads();
    float aq = bq[c], ak = bk[c], av = bv[c], as = bs[c];
    #pragma unroll 4
    for (int j = 0; j < DIM; j++) {
        float xj = xn[n][j];
        aq += xj * WQ[j * DIM + c];
        ak += xj * WK[j * DIM + c];
        av += xj * WV[j * DIM + c];
        as += xj * WS[j * DIM + c];
    }
    size_t o = node * DIM + c;
    qo[o] = aq * 0.35355339059327373f;   // 1/sqrt(8) folded in
    ko[o] = f2bf(ak);
    vo[o] = f2bf(av);
    hso[o] = hv + as;                    // residual + root skip folded
}

// ---------------- per-layer edge aggregation ----------------
// wave/node, 8 edges/iter; lane = (edge-group eg = lane>>3, channel quad cq = lane&7).
// Natural-order e buffer gathered via eidx (one 64B line per edge); k/v bf16 gathers
// (one 64B line each). Depth-2 data pipeline (2 iterations of loads in flight),
// index prefetch 3 ahead -> idx->data dependent chain is off the critical path.
__global__ __launch_bounds__(256) void k_aggr(const int* __restrict__ off, const int* __restrict__ eidx,
        const int* __restrict__ esrc, const u16* __restrict__ eb,
        const float* __restrict__ qb, const u16* __restrict__ kb, const u16* __restrict__ vb,
        const float* __restrict__ hs, float* __restrict__ out) {
    int tid = threadIdx.x;
    size_t node = (size_t)blockIdx.x * 4 + (tid >> 6);
    int lane = tid & 63;
    int eg = lane >> 3, cq = lane & 7, c0 = cq * 4;
    float4 qv = *(const float4*)&qb[node * DIM + c0];   // pre-scaled
    int o0 = off[node], o1 = off[node + 1];
    float4 nacc = {0.f, 0.f, 0.f, 0.f};
    float dacc = 0.f;

    // index stages A (iter 0), B (iter 1), C (iter 2)
    int pA = o0 + eg;  bool aA = pA < o1; int qAi = aA ? pA : o0;
    int eA = eidx[qAi], sA = esrc[qAi];
    int pB = pA + 8;   bool aB = pB < o1; int qBi = aB ? pB : o0;
    int eB = eidx[qBi], sB = esrc[qBi];
    int pC = pB + 8;   bool aC = pC < o1; int qCi = aC ? pC : o0;
    int eC = eidx[qCi], sC = esrc[qCi];

    // data stages A and B in flight
    uint2 dAe = *(const uint2*)&eb[(size_t)eA * DIM + c0];
    uint2 dAk = *(const uint2*)&kb[(size_t)sA * DIM + c0];
    uint2 dAv = *(const uint2*)&vb[(size_t)sA * DIM + c0];
    uint2 dBe = *(const uint2*)&eb[(size_t)eB * DIM + c0];
    uint2 dBk = *(const uint2*)&kb[(size_t)sB * DIM + c0];
    uint2 dBv = *(const uint2*)&vb[(size_t)sB * DIM + c0];

    for (int p = o0; p < o1; p += 8) {
        // issue data loads for stage C (2 iterations ahead)
        uint2 dCe = *(const uint2*)&eb[(size_t)eC * DIM + c0];
        uint2 dCk = *(const uint2*)&kb[(size_t)sC * DIM + c0];
        uint2 dCv = *(const uint2*)&vb[(size_t)sC * DIM + c0];
        // issue index loads for stage D (3 iterations ahead)
        int pD = pC + 8; bool aD = pD < o1; int qDi = aD ? pD : o0;
        int eD = eidx[qDi], sD = esrc[qDi];

        // compute stage A
        float e0 = bfhi2f(dAe.x << 16), e1 = bfhi2f(dAe.x & 0xFFFF0000u);
        float e2 = bfhi2f(dAe.y << 16), e3 = bfhi2f(dAe.y & 0xFFFF0000u);
        float k0 = bfhi2f(dAk.x << 16), k1 = bfhi2f(dAk.x & 0xFFFF0000u);
        float k2 = bfhi2f(dAk.y << 16), k3 = bfhi2f(dAk.y & 0xFFFF0000u);
        float v0 = bfhi2f(dAv.x << 16), v1 = bfhi2f(dAv.x & 0xFFFF0000u);
        float v2 = bfhi2f(dAv.y << 16), v3 = bfhi2f(dAv.y & 0xFFFF0000u);
        float a = qv.x * (k0 + e0);
        a = fmaf(qv.y, k1 + e1, a);
        a = fmaf(qv.z, k2 + e2, a);
        a = fmaf(qv.w, k3 + e3, a);
        a += __shfl_xor(a, 1);           // lane pair covers the head's 8 channels
        float ex = aA ? __expf(a) : 0.f;
        nacc.x = fmaf(ex, v0 + e0, nacc.x);
        nacc.y = fmaf(ex, v1 + e1, nacc.y);
        nacc.z = fmaf(ex, v2 + e2, nacc.z);
        nacc.w = fmaf(ex, v3 + e3, nacc.w);
        dacc += ex;

        // rotate pipeline
        aA = aB; dAe = dBe; dAk = dBk; dAv = dBv;
        aB = aC; dBe = dCe; dBk = dCk; dBv = dCv;
        aC = aD; eC = eD; sC = sD; pC = pD;
    }
    // reduce across the 8 edge-groups (cq preserved)
    #pragma unroll
    for (int d = 8; d < 64; d <<= 1) {
        nacc.x += __shfl_xor(nacc.x, d);
        nacc.y += __shfl_xor(nacc.y, d);
        nacc.z += __shfl_xor(nacc.z, d);
        nacc.w += __shfl_xor(nacc.w, d);
        dacc   += __shfl_xor(dacc, d);
    }
    if (eg == 0) {
        float inv = 1.f / (dacc + 1e-16f);
        float4 hv = *(const float4*)&hs[node * DIM + c0];
        float4 o;
        o.x = hv.x + nacc.x * inv;
        o.y = hv.y + nacc.y * inv;
        o.z = hv.z + nacc.z * inv;
        o.w = hv.w + nacc.w * inv;
        *(float4*)&out[node * DIM + c0] = o;
    }
}

extern "C" void kernel_launch(void* const* d_in, const int* in_sizes, int n_in,
                              void* d_out, int out_size, void* d_ws, size_t ws_size,
                              hipStream_t stream) {
    const float* x    = (const float*)d_in[0];
    const int*   ei   = (const int*)d_in[1];
    const int*   src  = ei;
    const int*   dst  = ei + N_EDGES;
    const float* elen = (const float*)d_in[2];
    const float* evec = (const float*)d_in[3];
    const float* niW  = (const float*)d_in[4];
    const float* nib  = (const float*)d_in[5];
    const float* lng  = (const float*)d_in[6];
    const float* lnb  = (const float*)d_in[7];
    const float* Wq   = (const float*)d_in[8];
    const float* bq   = (const float*)d_in[9];
    const float* Wk   = (const float*)d_in[10];
    const float* bk   = (const float*)d_in[11];
    const float* Wv   = (const float*)d_in[12];
    const float* bv   = (const float*)d_in[13];
    const float* We   = (const float*)d_in[14];
    const float* Wsk  = (const float*)d_in[15];
    const float* bsk  = (const float*)d_in[16];
    float* out = (float*)d_out;

    unsigned char* w = (unsigned char*)d_ws;
    auto alloc = [&](size_t bytes) -> void* {
        void* p = (void*)w; w += (bytes + 255) & ~(size_t)255; return p;
    };
    int*   off  = (int*)alloc((N_NODES + 1) * sizeof(int));
    int*   cnt  = (int*)alloc(N_NODES * sizeof(int));       // reused as cursor
    int*   bsum = (int*)alloc(512 * sizeof(int));
    int*   eidx = (int*)alloc((size_t)N_EDGES * sizeof(int));
    int*   esrc = (int*)alloc((size_t)N_EDGES * sizeof(int));
    float* h    = (float*)alloc((size_t)N_NODES * DIM * sizeof(float));
    float* qb   = (float*)alloc((size_t)N_NODES * DIM * sizeof(float));
    u16*   kb   = (u16*)alloc((size_t)N_NODES * DIM * sizeof(u16));
    u16*   vb   = (u16*)alloc((size_t)N_NODES * DIM * sizeof(u16));
    float* hsb  = (float*)alloc((size_t)N_NODES * DIM * sizeof(float));
    size_t used = (size_t)(w - (unsigned char*)d_ws);
    size_t e_full = (size_t)NLAYER * N_EDGES * DIM * sizeof(u16);
    size_t e_one  = (size_t)N_EDGES * DIM * sizeof(u16);
    bool full = (used + e_full) <= ws_size;
    u16* ebuf = (u16*)alloc(full ? e_full : e_one);

    const int EB = N_EDGES / 256;   // 12500
    const int NB = N_NODES / 8;     // 12500
    const int AB = N_NODES / 4;     // 25000
    const int nbScan = (N_NODES + 255) / 256;  // 391

    // CSR build
    hipMemsetAsync(cnt, 0, N_NODES * sizeof(int), stream);
    k_count<<<EB, 256, 0, stream>>>(dst, cnt);
    k_scanA<<<nbScan, 256, 0, stream>>>(cnt, off, bsum);
    k_scanB<<<1, 512, 0, stream>>>(bsum, nbScan);
    k_scanC<<<nbScan, 256, 0, stream>>>(off, bsum);
    hipMemsetAsync(cnt, 0, N_NODES * sizeof(int), stream);
    k_fill<<<EB, 256, 0, stream>>>(src, dst, off, cnt, eidx, esrc);

    // input projection
    k_init<<<NB, 256, 0, stream>>>(x, niW, nib, h);

    // edge-feature GEMM: fully sequential stream, natural edge order
    if (full) k_egemm<4><<<4096, 256, 0, stream>>>(elen, evec, We, ebuf);

    for (int l = 0; l < NLAYER; l++) {
        if (!full) k_egemm<1><<<4096, 256, 0, stream>>>(elen, evec, We + (size_t)l * EDF * DIM, ebuf);
        k_node<<<NB, 256, 0, stream>>>(h, lng + l * DIM, lnb + l * DIM,
                                       Wq + (size_t)l * DIM * DIM, bq + l * DIM,
                                       Wk + (size_t)l * DIM * DIM, bk + l * DIM,
                                       Wv + (size_t)l * DIM * DIM, bv + l * DIM,
                                       Wsk + (size_t)l * DIM * DIM, bsk + l * DIM,
                                       qb, kb, vb, hsb);
        const u16* el = full ? (ebuf + (size_t)l * N_EDGES * DIM) : ebuf;
        k_aggr<<<AB, 256, 0, stream>>>(off, eidx, esrc, el, qb, kb, vb, hsb,
                                       (l == NLAYER - 1) ? out : h);
    }
}

// Round 6
// 1309.196 us; speedup vs baseline: 1.2143x; 1.2026x over previous
//
#include <hip/hip_runtime.h>
#include <hip/hip_bf16.h>
#include <math.h>

#define N_NODES 100000
#define N_EDGES 3200000
#define NODE_IN 118
#define DIM 32
#define EDF 53
#define NLAYER 4

typedef __attribute__((ext_vector_type(8))) short short8;
typedef __attribute__((ext_vector_type(4))) float f32x4;
typedef unsigned short u16;
typedef unsigned int u32;

static __device__ __forceinline__ float bfhi2f(u32 hi) {
    union { u32 i; float f; } x; x.i = hi; return x.f;
}
static __device__ __forceinline__ u16 f2bf(float f) {
    union { float f; u32 i; } x; x.f = f;
    u32 i = x.i;
    return (u16)((i + 0x7FFFu + ((i >> 16) & 1u)) >> 16);
}
// packed f32x2 -> bf16x2 (D.lo = bf16(a), D.hi = bf16(b)), RNE
static __device__ __forceinline__ u32 pk2bf(float a, float b) {
    u32 r;
    asm("v_cvt_pk_bf16_f32 %0, %1, %2" : "=v"(r) : "v"(a), "v"(b));
    return r;
}

// ---------------- CSR build ----------------
__global__ __launch_bounds__(256) void k_count(const int* __restrict__ dst, int* __restrict__ cnt) {
    int e = blockIdx.x * 256 + threadIdx.x;
    atomicAdd(&cnt[dst[e]], 1);
}

__global__ __launch_bounds__(256) void k_scanA(const int* __restrict__ cnt, int* __restrict__ off,
                                               int* __restrict__ bsum) {
    __shared__ int s[256];
    int t = threadIdx.x; int i = blockIdx.x * 256 + t;
    int v = (i < N_NODES) ? cnt[i] : 0;
    s[t] = v; __syncthreads();
    for (int d = 1; d < 256; d <<= 1) {
        int x = (t >= d) ? s[t - d] : 0; __syncthreads();
        s[t] += x; __syncthreads();
    }
    if (i < N_NODES) off[i] = s[t] - v;
    if (t == 255) bsum[blockIdx.x] = s[t];
}

__global__ __launch_bounds__(512) void k_scanB(int* bsum, int nb) {
    __shared__ int s[512];
    int t = threadIdx.x;
    int v = (t < nb) ? bsum[t] : 0;
    s[t] = v; __syncthreads();
    for (int d = 1; d < 512; d <<= 1) {
        int x = (t >= d) ? s[t - d] : 0; __syncthreads();
        s[t] += x; __syncthreads();
    }
    if (t < nb) bsum[t] = s[t] - v;
}

__global__ __launch_bounds__(256) void k_scanC(int* off, const int* __restrict__ bsum) {
    int i = blockIdx.x * 256 + threadIdx.x;
    if (i < N_NODES) off[i] += bsum[blockIdx.x];
    if (i == 0) off[N_NODES] = N_EDGES;
}

__global__ __launch_bounds__(256) void k_fill(const int* __restrict__ src, const int* __restrict__ dst,
                                              const int* __restrict__ off, int* __restrict__ cur,
                                              int2* __restrict__ epk) {
    int e = blockIdx.x * 256 + threadIdx.x;
    int d = dst[e];
    int p = off[d] + atomicAdd(&cur[d], 1);
    epk[p] = make_int2(e, src[e]);   // CSR pos -> (natural edge id, source node)
}

// ---------------- node input projection: h = x @ W + b ----------------
__global__ __launch_bounds__(256) void k_init(const float* __restrict__ x, const float* __restrict__ W,
                                              const float* __restrict__ b, float* __restrict__ h) {
    __shared__ float Ws[NODE_IN * DIM];
    __shared__ float xs[8][NODE_IN];
    int t = threadIdx.x;
    for (int i = t; i < NODE_IN * DIM; i += 256) Ws[i] = W[i];
    int nb = blockIdx.x * 8;
    for (int i = t; i < 8 * NODE_IN; i += 256) {
        int n = i / NODE_IN, j = i % NODE_IN;
        xs[n][j] = x[(size_t)(nb + n) * NODE_IN + j];
    }
    __syncthreads();
    int n = t >> 5, c = t & 31;
    float acc = b[c];
    #pragma unroll 2
    for (int j = 0; j < NODE_IN; j++) acc += xs[n][j] * Ws[j * DIM + c];
    h[(size_t)(nb + n) * DIM + c] = acc;
}

// ---------------- edge-feature GEMM: fully sequential in AND out ----------------
template <int NL>
__global__ __launch_bounds__(256) void k_egemm(const float* __restrict__ elen, const float* __restrict__ evec,
                                               const float* __restrict__ We, u16* __restrict__ eout) {
    int tid = threadIdx.x;
    int lane = tid & 63;
    int wv = (blockIdx.x * 256 + tid) >> 6;
    int nw = (gridDim.x * 256) >> 6;
    int n15 = lane & 15, kb = lane >> 4;

    // We fragments (K padded to 64), VGPR-resident.
    short8 bf[2][2 * NL];
    for (int s = 0; s < 2; s++) {
        for (int t = 0; t < 2 * NL; t++) {
            int n = t * 16 + n15;
            int lay = n >> 5, c = n & 31;
            short8 tmp;
            #pragma unroll
            for (int j = 0; j < 8; j++) {
                int kk = s * 32 + kb * 8 + j;
                float w = (kk < EDF) ? We[(size_t)lay * EDF * DIM + (size_t)kk * DIM + c] : 0.f;
                ((u16*)&tmp)[j] = f2bf(w);
            }
            bf[s][t] = tmp;
        }
    }

    const int NT = N_EDGES / 16;

    auto LOADA = [&](int tile, float* fv) {
        int pos = tile * 16 + n15;
        const float* lp = elen + (size_t)pos * 50;
        {
            const float2* p2 = (const float2*)(lp + kb * 8);
            #pragma unroll
            for (int j = 0; j < 4; j++) { float2 t2 = p2[j]; fv[2 * j] = t2.x; fv[2 * j + 1] = t2.y; }
        }
        if (kb < 2) {
            const float2* p2 = (const float2*)(lp + 32 + kb * 8);
            #pragma unroll
            for (int j = 0; j < 4; j++) { float2 t2 = p2[j]; fv[8 + 2 * j] = t2.x; fv[8 + 2 * j + 1] = t2.y; }
        } else if (kb == 2) {
            float2 t2 = *(const float2*)(lp + 48);
            const float* vp = evec + (size_t)pos * 3;
            fv[8] = t2.x; fv[9] = t2.y; fv[10] = vp[0]; fv[11] = vp[1]; fv[12] = vp[2];
            fv[13] = 0.f; fv[14] = 0.f; fv[15] = 0.f;
        } else {
            #pragma unroll
            for (int j = 8; j < 16; j++) fv[j] = 0.f;
        }
    };

    float cur[16];
    if (wv < NT) LOADA(wv, cur);

    for (int tile = wv; tile < NT; tile += nw) {
        int nxt = tile + nw;
        float nx[16];
        if (nxt < NT) LOADA(nxt, nx);   // next-tile loads issued before this tile's stores

        union { short8 s; u32 u[4]; } A0, A1;
        A0.u[0] = pk2bf(cur[0], cur[1]);  A0.u[1] = pk2bf(cur[2], cur[3]);
        A0.u[2] = pk2bf(cur[4], cur[5]);  A0.u[3] = pk2bf(cur[6], cur[7]);
        A1.u[0] = pk2bf(cur[8], cur[9]);  A1.u[1] = pk2bf(cur[10], cur[11]);
        A1.u[2] = pk2bf(cur[12], cur[13]); A1.u[3] = pk2bf(cur[14], cur[15]);

        size_t rowbase = ((size_t)tile * 16 + n15) * DIM;
        #pragma unroll
        for (int t = 0; t < 2 * NL; t++) {
            f32x4 z = {0.f, 0.f, 0.f, 0.f};
            // swapped operands: C col = lane&15 = edge, C row = kb*4 + r = channel
            z = __builtin_amdgcn_mfma_f32_16x16x32_bf16(bf[0][t], A0.s, z, 0, 0, 0);
            z = __builtin_amdgcn_mfma_f32_16x16x32_bf16(bf[1][t], A1.s, z, 0, 0, 0);
            int lay = t >> 1;
            int ch = (t & 1) * 16 + kb * 4;
            uint2 sv = { pk2bf(z[0], z[1]), pk2bf(z[2], z[3]) };
            *(uint2*)&eout[(size_t)lay * N_EDGES * DIM + rowbase + ch] = sv;
        }

        #pragma unroll
        for (int j = 0; j < 16; j++) cur[j] = nx[j];
    }
}

// ---------------- per-layer node transform: LN + q,kv,h+skip ----------------
// q pre-scaled by 1/sqrt(C); k,v bf16 interleaved per node (128B row); hs = h + skip.
__global__ __launch_bounds__(256) void k_node(const float* __restrict__ h,
        const float* __restrict__ g, const float* __restrict__ bta,
        const float* __restrict__ Wq, const float* __restrict__ bq,
        const float* __restrict__ Wk, const float* __restrict__ bk,
        const float* __restrict__ Wv, const float* __restrict__ bv,
        const float* __restrict__ Ws, const float* __restrict__ bs,
        float* __restrict__ qo, u16* __restrict__ kvo, float* __restrict__ hso) {
    __shared__ float WQ[DIM * DIM], WK[DIM * DIM], WV[DIM * DIM], WS[DIM * DIM];
    __shared__ float xn[8][DIM];
    int t = threadIdx.x;
    for (int i = t; i < DIM * DIM; i += 256) { WQ[i] = Wq[i]; WK[i] = Wk[i]; WV[i] = Wv[i]; WS[i] = Ws[i]; }
    int n = t >> 5, c = t & 31;
    size_t node = (size_t)blockIdx.x * 8 + n;
    float hv = h[node * DIM + c];
    float s1 = hv;
    for (int d = 1; d < 32; d <<= 1) s1 += __shfl_xor(s1, d, 64);
    float mu = s1 * (1.f / 32.f);
    float dv = hv - mu;
    float s2 = dv * dv;
    for (int d = 1; d < 32; d <<= 1) s2 += __shfl_xor(s2, d, 64);
    float inv = rsqrtf(s2 * (1.f / 32.f) + 1e-5f);
    float xv = dv * inv * g[c] + bta[c];
    xn[n][c] = xv;
    __syncthreads();
    float aq = bq[c], ak = bk[c], av = bv[c], as = bs[c];
    #pragma unroll 4
    for (int j = 0; j < DIM; j++) {
        float xj = xn[n][j];
        aq += xj * WQ[j * DIM + c];
        ak += xj * WK[j * DIM + c];
        av += xj * WV[j * DIM + c];
        as += xj * WS[j * DIM + c];
    }
    size_t o = node * DIM + c;
    qo[o] = aq * 0.35355339059327373f;     // 1/sqrt(8) folded in
    kvo[node * 64 + c]      = f2bf(ak);    // k | v interleaved: one 128B row per node
    kvo[node * 64 + 32 + c] = f2bf(av);
    hso[o] = hv + as;                      // residual + root skip folded
}

// ---------------- per-layer edge aggregation: head-per-lane, 16 edges/iter ----------------
// lane = (edge-group eg = lane>>2, head hq = lane&3 -> channels hq*8..hq*8+7).
// Alpha dot product is fully lane-local (C=8 contiguous channels/head): zero shuffles
// per edge. Depth-2 data pipeline, index prefetch 3 stages ahead. One 36-shuffle
// cross-edge-group reduction per node.
__global__ __launch_bounds__(256) void k_aggr(const int* __restrict__ off, const int2* __restrict__ epk,
        const u16* __restrict__ eb, const float* __restrict__ qb, const u16* __restrict__ kvb,
        const float* __restrict__ hs, float* __restrict__ out) {
    int tid = threadIdx.x;
    size_t node = (size_t)blockIdx.x * 4 + (tid >> 6);
    int lane = tid & 63;
    int eg = lane >> 2, hq = lane & 3, c0 = hq * 8;
    float4 q0 = *(const float4*)&qb[node * DIM + c0];
    float4 q1 = *(const float4*)&qb[node * DIM + c0 + 4];
    int o0 = off[node], o1 = off[node + 1];
    int safe = (o0 < N_EDGES) ? o0 : (N_EDGES - 1);
    float n0=0.f,n1=0.f,n2=0.f,n3=0.f,n4=0.f,n5=0.f,n6=0.f,n7=0.f;
    float dacc = 0.f;

    // index stages A (iter 0), B (+1), C (+2)
    int pA = o0 + eg;  bool aA = pA < o1; int2 xA = epk[aA ? pA : safe];
    int pB = pA + 16;  bool aB = pB < o1; int2 xB = epk[aB ? pB : safe];
    int pC = pB + 16;  bool aC = pC < o1; int2 xC = epk[aC ? pC : safe];

    // data stages A and B in flight (uint4 = 16B = this head's 8 bf16 channels)
    uint4 dAe = *(const uint4*)&eb[(size_t)xA.x * DIM + c0];
    uint4 dAk = *(const uint4*)&kvb[(size_t)xA.y * 64 + c0];
    uint4 dAv = *(const uint4*)&kvb[(size_t)xA.y * 64 + 32 + c0];
    uint4 dBe = *(const uint4*)&eb[(size_t)xB.x * DIM + c0];
    uint4 dBk = *(const uint4*)&kvb[(size_t)xB.y * 64 + c0];
    uint4 dBv = *(const uint4*)&kvb[(size_t)xB.y * 64 + 32 + c0];

    for (int p = o0; p < o1; p += 16) {
        // stage C data loads (2 iterations ahead)
        uint4 dCe = *(const uint4*)&eb[(size_t)xC.x * DIM + c0];
        uint4 dCk = *(const uint4*)&kvb[(size_t)xC.y * 64 + c0];
        uint4 dCv = *(const uint4*)&kvb[(size_t)xC.y * 64 + 32 + c0];
        // stage D index load (3 iterations ahead)
        int pD = pC + 16; bool aD = pD < o1; int2 xD = epk[aD ? pD : safe];

        // compute stage A (all lane-local)
        float e0 = bfhi2f(dAe.x << 16), e1 = bfhi2f(dAe.x & 0xFFFF0000u);
        float e2 = bfhi2f(dAe.y << 16), e3 = bfhi2f(dAe.y & 0xFFFF0000u);
        float e4 = bfhi2f(dAe.z << 16), e5 = bfhi2f(dAe.z & 0xFFFF0000u);
        float e6 = bfhi2f(dAe.w << 16), e7 = bfhi2f(dAe.w & 0xFFFF0000u);
        float k0 = bfhi2f(dAk.x << 16), k1 = bfhi2f(dAk.x & 0xFFFF0000u);
        float k2 = bfhi2f(dAk.y << 16), k3 = bfhi2f(dAk.y & 0xFFFF0000u);
        float k4 = bfhi2f(dAk.z << 16), k5 = bfhi2f(dAk.z & 0xFFFF0000u);
        float k6 = bfhi2f(dAk.w << 16), k7 = bfhi2f(dAk.w & 0xFFFF0000u);
        float v0 = bfhi2f(dAv.x << 16), v1 = bfhi2f(dAv.x & 0xFFFF0000u);
        float v2 = bfhi2f(dAv.y << 16), v3 = bfhi2f(dAv.y & 0xFFFF0000u);
        float v4 = bfhi2f(dAv.z << 16), v5 = bfhi2f(dAv.z & 0xFFFF0000u);
        float v6 = bfhi2f(dAv.w << 16), v7 = bfhi2f(dAv.w & 0xFFFF0000u);
        float a =      q0.x * (k0 + e0);
        a = fmaf(q0.y, k1 + e1, a);
        a = fmaf(q0.z, k2 + e2, a);
        a = fmaf(q0.w, k3 + e3, a);
        a = fmaf(q1.x, k4 + e4, a);
        a = fmaf(q1.y, k5 + e5, a);
        a = fmaf(q1.z, k6 + e6, a);
        a = fmaf(q1.w, k7 + e7, a);
        float ex = aA ? __expf(a) : 0.f;
        n0 = fmaf(ex, v0 + e0, n0); n1 = fmaf(ex, v1 + e1, n1);
        n2 = fmaf(ex, v2 + e2, n2); n3 = fmaf(ex, v3 + e3, n3);
        n4 = fmaf(ex, v4 + e4, n4); n5 = fmaf(ex, v5 + e5, n5);
        n6 = fmaf(ex, v6 + e6, n6); n7 = fmaf(ex, v7 + e7, n7);
        dacc += ex;

        // rotate pipeline
        aA = aB; dAe = dBe; dAk = dBk; dAv = dBv;
        dBe = dCe; dBk = dCk; dBv = dCv;
        aB = aC; xC = xD; aC = aD; pC = pD;
    }
    // reduce across the 16 edge-groups (head lanes preserved: xor 4,8,16,32)
    #pragma unroll
    for (int d = 4; d < 64; d <<= 1) {
        n0 += __shfl_xor(n0, d); n1 += __shfl_xor(n1, d);
        n2 += __shfl_xor(n2, d); n3 += __shfl_xor(n3, d);
        n4 += __shfl_xor(n4, d); n5 += __shfl_xor(n5, d);
        n6 += __shfl_xor(n6, d); n7 += __shfl_xor(n7, d);
        dacc += __shfl_xor(dacc, d);
    }
    if (eg == 0) {
        float inv = 1.f / (dacc + 1e-16f);
        float4 h0 = *(const float4*)&hs[node * DIM + c0];
        float4 h1 = *(const float4*)&hs[node * DIM + c0 + 4];
        float4 o0v = { h0.x + n0 * inv, h0.y + n1 * inv, h0.z + n2 * inv, h0.w + n3 * inv };
        float4 o1v = { h1.x + n4 * inv, h1.y + n5 * inv, h1.z + n6 * inv, h1.w + n7 * inv };
        *(float4*)&out[node * DIM + c0] = o0v;
        *(float4*)&out[node * DIM + c0 + 4] = o1v;
    }
}

extern "C" void kernel_launch(void* const* d_in, const int* in_sizes, int n_in,
                              void* d_out, int out_size, void* d_ws, size_t ws_size,
                              hipStream_t stream) {
    const float* x    = (const float*)d_in[0];
    const int*   ei   = (const int*)d_in[1];
    const int*   src  = ei;
    const int*   dst  = ei + N_EDGES;
    const float* elen = (const float*)d_in[2];
    const float* evec = (const float*)d_in[3];
    const float* niW  = (const float*)d_in[4];
    const float* nib  = (const float*)d_in[5];
    const float* lng  = (const float*)d_in[6];
    const float* lnb  = (const float*)d_in[7];
    const float* Wq   = (const float*)d_in[8];
    const float* bq   = (const float*)d_in[9];
    const float* Wk   = (const float*)d_in[10];
    const float* bk   = (const float*)d_in[11];
    const float* Wv   = (const float*)d_in[12];
    const float* bv   = (const float*)d_in[13];
    const float* We   = (const float*)d_in[14];
    const float* Wsk  = (const float*)d_in[15];
    const float* bsk  = (const float*)d_in[16];
    float* out = (float*)d_out;

    unsigned char* w = (unsigned char*)d_ws;
    auto alloc = [&](size_t bytes) -> void* {
        void* p = (void*)w; w += (bytes + 255) & ~(size_t)255; return p;
    };
    int*   off  = (int*)alloc((N_NODES + 1) * sizeof(int));
    int*   cnt  = (int*)alloc(N_NODES * sizeof(int));       // reused as cursor
    int*   bsum = (int*)alloc(512 * sizeof(int));
    int2*  epk  = (int2*)alloc((size_t)N_EDGES * sizeof(int2));
    float* h    = (float*)alloc((size_t)N_NODES * DIM * sizeof(float));
    float* qb   = (float*)alloc((size_t)N_NODES * DIM * sizeof(float));
    u16*   kvb  = (u16*)alloc((size_t)N_NODES * 64 * sizeof(u16));
    float* hsb  = (float*)alloc((size_t)N_NODES * DIM * sizeof(float));
    size_t used = (size_t)(w - (unsigned char*)d_ws);
    size_t e_full = (size_t)NLAYER * N_EDGES * DIM * sizeof(u16);
    size_t e_one  = (size_t)N_EDGES * DIM * sizeof(u16);
    bool full = (used + e_full) <= ws_size;
    u16* ebuf = (u16*)alloc(full ? e_full : e_one);

    const int EB = N_EDGES / 256;   // 12500
    const int NB = N_NODES / 8;     // 12500
    const int AB = N_NODES / 4;     // 25000
    const int nbScan = (N_NODES + 255) / 256;  // 391

    // CSR build
    hipMemsetAsync(cnt, 0, N_NODES * sizeof(int), stream);
    k_count<<<EB, 256, 0, stream>>>(dst, cnt);
    k_scanA<<<nbScan, 256, 0, stream>>>(cnt, off, bsum);
    k_scanB<<<1, 512, 0, stream>>>(bsum, nbScan);
    k_scanC<<<nbScan, 256, 0, stream>>>(off, bsum);
    hipMemsetAsync(cnt, 0, N_NODES * sizeof(int), stream);
    k_fill<<<EB, 256, 0, stream>>>(src, dst, off, cnt, epk);

    // input projection
    k_init<<<NB, 256, 0, stream>>>(x, niW, nib, h);

    // edge-feature GEMM: fully sequential stream, natural edge order
    if (full) k_egemm<4><<<4096, 256, 0, stream>>>(elen, evec, We, ebuf);

    for (int l = 0; l < NLAYER; l++) {
        if (!full) k_egemm<1><<<4096, 256, 0, stream>>>(elen, evec, We + (size_t)l * EDF * DIM, ebuf);
        k_node<<<NB, 256, 0, stream>>>(h, lng + l * DIM, lnb + l * DIM,
                                       Wq + (size_t)l * DIM * DIM, bq + l * DIM,
                                       Wk + (size_t)l * DIM * DIM, bk + l * DIM,
                                       Wv + (size_t)l * DIM * DIM, bv + l * DIM,
                                       Wsk + (size_t)l * DIM * DIM, bsk + l * DIM,
                                       qb, kvb, hsb);
        const u16* el = full ? (ebuf + (size_t)l * N_EDGES * DIM) : ebuf;
        k_aggr<<<AB, 256, 0, stream>>>(off, epk, el, qb, kvb, hsb,
                                       (l == NLAYER - 1) ? out : h);
    }
}